// Round 1
// baseline (1117.014 us; speedup 1.0000x reference)
//
#include <hip/hip_runtime.h>
#include <math.h>

// Problem constants
#define TT 4
#define VV 4096
#define EE 4096
#define KK 32
#define DD 8
#define HH 16
#define BERTD 768
#define CATD 784
#define NH 196     // CAT/4 hidden units of EdgeConv MLP
#define NTOT 260   // 196 hidden + 64 pe (Wih_m projection)

__device__ __forceinline__ float sigmoidf_(float x){ return 1.0f/(1.0f+expf(-x)); }
__device__ __forceinline__ float dot4_(float4 a, float4 b){
  return fmaf(a.x,b.x, fmaf(a.y,b.y, fmaf(a.z,b.z, a.w*b.w)));
}

// ---------------------------------------------------------------------------
// K1: price LSTM. (T,V,1) -> new_prices (T,V,16). One thread per vertex.
// ---------------------------------------------------------------------------
__global__ void k1_price_lstm(const float* __restrict__ prices,
                              const float* __restrict__ Wih, const float* __restrict__ Whh,
                              const float* __restrict__ bih, const float* __restrict__ bhh,
                              float* __restrict__ np_out){
  __shared__ float sWhh[64*16];
  __shared__ float sWih[64];
  __shared__ float sb[64];
  int tid = threadIdx.x;
  for (int i = tid; i < 64*16; i += 256) sWhh[i] = Whh[i];
  if (tid < 64){ sWih[tid] = Wih[tid]; sb[tid] = bih[tid] + bhh[tid]; }
  __syncthreads();
  int v = blockIdx.x*256 + tid;
  float h[16], c[16];
#pragma unroll
  for (int d=0; d<16; ++d){ h[d]=0.f; c[d]=0.f; }
  for (int t=0; t<TT; ++t){
    float x = prices[t*VV + v];
    float g[64];
#pragma unroll
    for (int j=0; j<64; ++j){
      float a = fmaf(x, sWih[j], sb[j]);
#pragma unroll
      for (int d=0; d<16; ++d) a = fmaf(h[d], sWhh[j*16+d], a);
      g[j] = a;
    }
#pragma unroll
    for (int d=0; d<16; ++d){
      float ig = sigmoidf_(g[d]);
      float fg = sigmoidf_(g[16+d]);
      float gg = tanhf(g[32+d]);
      float og = sigmoidf_(g[48+d]);
      c[d] = fmaf(fg, c[d], ig*gg);
      float hv = og * tanhf(c[d]);
      h[d] = hv;
      np_out[(size_t)(t*VV+v)*16 + d] = hv;
    }
  }
}

// ---------------------------------------------------------------------------
// K2: VertexConv. One block (256 thr) per (t,e). Output he_emb (T,E,16).
// ---------------------------------------------------------------------------
__global__ void k2_vertex_conv(const float* __restrict__ np,
                               const int* __restrict__ mem,
                               const float* __restrict__ tw, const float* __restrict__ tb,
                               const float* __restrict__ cw, const float* __restrict__ cb,
                               float* __restrict__ he_emb){
  int te = blockIdx.x;            // t*E + e
  int t  = te >> 12;
  __shared__ float reg[32][16];
  __shared__ float mult[32][32];
  __shared__ float trans[32][16];
  int tid = threadIdx.x;
  // gather member price embeddings: 32 members x 16 feats
  for (int i = tid; i < 512; i += 256){
    int k = i >> 4, d = i & 15;
    int vid = mem[te*32 + k];
    reg[k][d] = np[(size_t)(t*VV + vid)*16 + d];
  }
  __syncthreads();
  // mult[k][j] = softmax_j( reg[k]·tw[k][j] + tb[k][j] )
  int k = tid >> 3, s = tid & 7;     // 32 rows x 8 lanes, 4 j's per lane
  const float4* rg4 = reinterpret_cast<const float4*>(&reg[k][0]);
  float4 r0 = rg4[0], r1 = rg4[1], r2 = rg4[2], r3 = rg4[3];
  float mv[4];
#pragma unroll
  for (int jj=0; jj<4; ++jj){
    int j = s*4 + jj;
    const float4* w4 = reinterpret_cast<const float4*>(tw + (size_t)(k*32 + j)*16);
    mv[jj] = tb[k*32+j] + dot4_(r0,w4[0]) + dot4_(r1,w4[1]) + dot4_(r2,w4[2]) + dot4_(r3,w4[3]);
  }
  float mx = fmaxf(fmaxf(mv[0],mv[1]), fmaxf(mv[2],mv[3]));
#pragma unroll
  for (int off=1; off<8; off<<=1) mx = fmaxf(mx, __shfl_xor(mx, off));
  float sum = 0.f;
#pragma unroll
  for (int jj=0; jj<4; ++jj){ mv[jj] = expf(mv[jj]-mx); sum += mv[jj]; }
#pragma unroll
  for (int off=1; off<8; off<<=1) sum += __shfl_xor(sum, off);
  float inv = 1.f/sum;
#pragma unroll
  for (int jj=0; jj<4; ++jj) mult[k][s*4+jj] = mv[jj]*inv;
  __syncthreads();
  // trans[k][d] = sum_j mult[k][j]*reg[j][d]
  for (int i = tid; i < 512; i += 256){
    int kk2 = i >> 4, d = i & 15;
    float a = 0.f;
#pragma unroll
    for (int j=0; j<32; ++j) a = fmaf(mult[kk2][j], reg[j][d], a);
    trans[kk2][d] = a;
  }
  __syncthreads();
  // he_emb[d] = cb + sum_k cw[k]*trans[k][d]
  if (tid < 16){
    float a = cb[0];
#pragma unroll
    for (int kq=0; kq<32; ++kq) a = fmaf(cw[kq], trans[kq][tid], a);
    he_emb[(size_t)te*16 + tid] = a;
  }
}

// ---------------------------------------------------------------------------
// K3: fused GEMM. C (16384 x 260) = [he_emb | node_embs] (16384 x 784)
//                                   @ [ec_w1 ; Wih_m]^T  (784 x 260)
// cols 0..195 = pre-relu hidden (+b1), cols 196..259 = pe (no bias).
// 64x64 tile, BK=16, 4x4 register micro-tile.
// ---------------------------------------------------------------------------
__global__ void k3_gemm(const float* __restrict__ he_emb, const float* __restrict__ node,
                        const float* __restrict__ w1, const float* __restrict__ b1,
                        const float* __restrict__ wm, float* __restrict__ C){
  __shared__ float As[16][64];
  __shared__ float Bs[16][64];
  int m0 = blockIdx.y*64, n0 = blockIdx.x*64;
  int tid = threadIdx.x;
  int tx = tid & 15, ty = tid >> 4;
  int lm = tid >> 2;           // 0..63 (row within tile)
  int lk = (tid & 3) * 4;      // 0,4,8,12 (k-quad base)
  float acc[4][4] = {{0.f}};
  for (int kk = 0; kk < 49; ++kk){
    int kbase = kk*16;
    // A tile: row m0+lm, k = kbase+lk .. +3
    {
      int m = m0 + lm;
      int kcol = kbase + lk;
      float4 av;
      if (kcol < 16) av = *reinterpret_cast<const float4*>(&he_emb[(size_t)m*16 + kcol]);
      else           av = *reinterpret_cast<const float4*>(&node[(size_t)m*BERTD + (kcol-16)]);
      As[lk+0][lm]=av.x; As[lk+1][lm]=av.y; As[lk+2][lm]=av.z; As[lk+3][lm]=av.w;
    }
    // B tile: row n0+lm of the stacked weight matrix
    {
      int n = n0 + lm;
      int kcol = kbase + lk;
      float4 bv = make_float4(0.f,0.f,0.f,0.f);
      if (n < NH)        bv = *reinterpret_cast<const float4*>(&w1[(size_t)n*CATD + kcol]);
      else if (n < NTOT) bv = *reinterpret_cast<const float4*>(&wm[(size_t)(n-NH)*CATD + kcol]);
      Bs[lk+0][lm]=bv.x; Bs[lk+1][lm]=bv.y; Bs[lk+2][lm]=bv.z; Bs[lk+3][lm]=bv.w;
    }
    __syncthreads();
#pragma unroll
    for (int k=0; k<16; ++k){
      float4 av = *reinterpret_cast<const float4*>(&As[k][ty*4]);
      float4 bv = *reinterpret_cast<const float4*>(&Bs[k][tx*4]);
      float a[4] = {av.x, av.y, av.z, av.w};
      float b[4] = {bv.x, bv.y, bv.z, bv.w};
#pragma unroll
      for (int i=0;i<4;++i)
#pragma unroll
        for (int j=0;j<4;++j) acc[i][j] = fmaf(a[i], b[j], acc[i][j]);
    }
    __syncthreads();
  }
#pragma unroll
  for (int i=0;i<4;++i){
    int m = m0 + ty*4 + i;
#pragma unroll
    for (int j=0;j<4;++j){
      int n = n0 + tx*4 + j;
      if (n < NTOT){
        float v = acc[i][j];
        if (n < NH) v += b1[n];
        C[(size_t)m*NTOT + n] = v;
      }
    }
  }
}

// ---------------------------------------------------------------------------
// K3b: per-hyperedge score: esc[m] = b2 + sum_n relu(hid[m,n]) * w2[n]
// one wave per row.
// ---------------------------------------------------------------------------
__global__ void k3b_edge_score(const float* __restrict__ C, const float* __restrict__ w2,
                               const float* __restrict__ b2, float* __restrict__ esc){
  int tid = threadIdx.x;
  int lane = tid & 63;
  int row = blockIdx.x*4 + (tid >> 6);
  const float* cr = &C[(size_t)row*NTOT];
  float a = 0.f;
  for (int n = lane; n < NH; n += 64) a = fmaf(fmaxf(cr[n], 0.f), w2[n], a);
#pragma unroll
  for (int off=32; off; off>>=1) a += __shfl_xor(a, off);
  if (lane == 0) esc[row] = a + b2[0];
}

// ---------------------------------------------------------------------------
// K4: per-(t,v): softmax over D=8 edge scores, blend projected rows pe
// (cols 196..259 of C) -> g_in (T,V,64). One wave per (t,v).
// ---------------------------------------------------------------------------
__global__ void k4_edge_gather(const int* __restrict__ ve, const float* __restrict__ esc,
                               const float* __restrict__ C, float* __restrict__ g_in){
  int tid = threadIdx.x;
  int lane = tid & 63;
  int tv = blockIdx.x*4 + (tid >> 6);
  int t = tv >> 12;
  const int* vp = &ve[(size_t)tv*8];
  int e[8]; float w[8];
  float mx = -1e30f;
#pragma unroll
  for (int d=0; d<8; ++d){
    e[d] = vp[d];
    w[d] = esc[(t<<12) + e[d]];
    mx = fmaxf(mx, w[d]);
  }
  float s = 0.f;
#pragma unroll
  for (int d=0; d<8; ++d){ w[d] = expf(w[d]-mx); s += w[d]; }
  float inv = 1.f/s;
  float a = 0.f;
#pragma unroll
  for (int d=0; d<8; ++d)
    a = fmaf(w[d], C[(size_t)((t<<12) + e[d])*NTOT + NH + lane], a);
  g_in[(size_t)tv*64 + lane] = a*inv;
}

// ---------------------------------------------------------------------------
// K5: second LSTM over (T, V, g_in 64-wide gates-input) + residual new_prices.
// One thread per vertex. la = lstm_out + new_prices.
// ---------------------------------------------------------------------------
__global__ void k5_lstm2(const float* __restrict__ g_in, const float* __restrict__ Whh,
                         const float* __restrict__ bih, const float* __restrict__ bhh,
                         const float* __restrict__ np, float* __restrict__ la){
  __shared__ float sWhh[64*16];
  __shared__ float sb[64];
  int tid = threadIdx.x;
  for (int i = tid; i < 1024; i += 256) sWhh[i] = Whh[i];
  if (tid < 64) sb[tid] = bih[tid] + bhh[tid];
  __syncthreads();
  int v = blockIdx.x*256 + tid;
  float h[16], c[16];
#pragma unroll
  for (int d=0; d<16; ++d){ h[d]=0.f; c[d]=0.f; }
  for (int t=0; t<TT; ++t){
    const float* gi = &g_in[(size_t)(t*VV+v)*64];
    float g[64];
#pragma unroll
    for (int j4=0; j4<16; ++j4){
      float4 gv = *reinterpret_cast<const float4*>(&gi[j4*4]);
      g[j4*4+0]=gv.x; g[j4*4+1]=gv.y; g[j4*4+2]=gv.z; g[j4*4+3]=gv.w;
    }
#pragma unroll
    for (int j=0; j<64; ++j){
      float a = g[j] + sb[j];
#pragma unroll
      for (int d=0; d<16; ++d) a = fmaf(h[d], sWhh[j*16+d], a);
      g[j] = a;
    }
#pragma unroll
    for (int d=0; d<16; ++d){
      float ig = sigmoidf_(g[d]);
      float fg = sigmoidf_(g[16+d]);
      float gg = tanhf(g[32+d]);
      float og = sigmoidf_(g[48+d]);
      c[d] = fmaf(fg, c[d], ig*gg);
      float hv = og * tanhf(c[d]);
      h[d] = hv;
      la[(size_t)(t*VV+v)*16 + d] = hv + np[(size_t)(t*VV+v)*16 + d];
    }
  }
}

// ---------------------------------------------------------------------------
// K6: torchnlp 'general' attention over T steps + tanh proj + final FC.
// One thread per vertex. Output (V,2) f32.
// ---------------------------------------------------------------------------
__global__ void k6_attn_fc(const float* __restrict__ la, const float* __restrict__ ain,
                           const float* __restrict__ aout, const float* __restrict__ fcw,
                           const float* __restrict__ fcb, float* __restrict__ out){
  __shared__ float s_ain[256];
  __shared__ float s_aout[512];
  __shared__ float s_fc[32];
  __shared__ float s_fcb[2];
  int tid = threadIdx.x;
  s_ain[tid] = ain[tid];
  for (int i = tid; i < 512; i += 256) s_aout[i] = aout[i];
  if (tid < 32) s_fc[tid] = fcw[tid];
  if (tid < 2)  s_fcb[tid] = fcb[tid];
  __syncthreads();
  int v = blockIdx.x*256 + tid;
  float lr[4][16];
#pragma unroll
  for (int t=0; t<4; ++t){
    const float4* p = reinterpret_cast<const float4*>(&la[(size_t)(t*VV+v)*16]);
    float4 a0=p[0], a1=p[1], a2=p[2], a3=p[3];
    lr[t][0]=a0.x; lr[t][1]=a0.y; lr[t][2]=a0.z; lr[t][3]=a0.w;
    lr[t][4]=a1.x; lr[t][5]=a1.y; lr[t][6]=a1.z; lr[t][7]=a1.w;
    lr[t][8]=a2.x; lr[t][9]=a2.y; lr[t][10]=a2.z; lr[t][11]=a2.w;
    lr[t][12]=a3.x; lr[t][13]=a3.y; lr[t][14]=a3.z; lr[t][15]=a3.w;
  }
  float q[16];
#pragma unroll
  for (int j=0; j<16; ++j){
    float a = 0.f;
#pragma unroll
    for (int d=0; d<16; ++d) a = fmaf(lr[3][d], s_ain[j*16+d], a);
    q[j] = a;
  }
  float aw[4]; float mx = -1e30f;
#pragma unroll
  for (int t=0; t<4; ++t){
    float a = 0.f;
#pragma unroll
    for (int d=0; d<16; ++d) a = fmaf(q[d], lr[t][d], a);
    aw[t] = a; mx = fmaxf(mx, a);
  }
  float sum = 0.f;
#pragma unroll
  for (int t=0; t<4; ++t){ aw[t] = expf(aw[t]-mx); sum += aw[t]; }
  float inv = 1.f/sum;
  float mix[16];
#pragma unroll
  for (int d=0; d<16; ++d){
    float a = 0.f;
#pragma unroll
    for (int t=0; t<4; ++t) a = fmaf(aw[t], lr[t][d], a);
    mix[d] = a*inv;
  }
  float at[16];
#pragma unroll
  for (int j=0; j<16; ++j){
    float a = 0.f;
#pragma unroll
    for (int d=0; d<16; ++d) a = fmaf(mix[d], s_aout[j*32+d], a);
#pragma unroll
    for (int d=0; d<16; ++d) a = fmaf(q[d], s_aout[j*32+16+d], a);
    at[j] = tanhf(a);
  }
#pragma unroll
  for (int r=0; r<2; ++r){
    float a = s_fcb[r];
#pragma unroll
    for (int j=0; j<16; ++j) a = fmaf(at[j], s_fc[r*16+j], a);
    out[(size_t)v*2 + r] = a;
  }
}

// ---------------------------------------------------------------------------
extern "C" void kernel_launch(void* const* d_in, const int* in_sizes, int n_in,
                              void* d_out, int out_size, void* d_ws, size_t ws_size,
                              hipStream_t stream){
  const float* prices = (const float*)d_in[0];
  const float* node   = (const float*)d_in[1];
  const int*   mem    = (const int*)d_in[2];
  const int*   ve     = (const int*)d_in[3];
  const float* Wih_p  = (const float*)d_in[4];
  const float* Whh_p  = (const float*)d_in[5];
  const float* bih_p  = (const float*)d_in[6];
  const float* bhh_p  = (const float*)d_in[7];
  const float* Wih_m  = (const float*)d_in[8];
  const float* Whh_m  = (const float*)d_in[9];
  const float* bih_m  = (const float*)d_in[10];
  const float* bhh_m  = (const float*)d_in[11];
  const float* tw     = (const float*)d_in[12];
  const float* tb     = (const float*)d_in[13];
  const float* cw     = (const float*)d_in[14];
  const float* cb     = (const float*)d_in[15];
  const float* w1     = (const float*)d_in[16];
  const float* b1     = (const float*)d_in[17];
  const float* w2     = (const float*)d_in[18];
  const float* b2     = (const float*)d_in[19];
  const float* ain    = (const float*)d_in[20];
  const float* aout   = (const float*)d_in[21];
  const float* fcw    = (const float*)d_in[22];
  const float* fcb    = (const float*)d_in[23];

  // workspace layout (floats); total ≈ 25.5 MB
  float* np_buf = (float*)d_ws;                       // T*V*16
  float* he_emb = np_buf + (size_t)TT*VV*HH;          // T*E*16
  float* Cbuf   = he_emb + (size_t)TT*EE*HH;          // 16384*260
  float* esc    = Cbuf   + (size_t)TT*EE*NTOT;        // 16384
  float* g_in   = esc    + (size_t)TT*EE;             // T*V*64
  // (end of used ws)

  k1_price_lstm<<<VV/256, 256, 0, stream>>>(prices, Wih_p, Whh_p, bih_p, bhh_p, np_buf);
  k2_vertex_conv<<<TT*EE, 256, 0, stream>>>(np_buf, mem, tw, tb, cw, cb, he_emb);
  k3_gemm<<<dim3(5, (TT*EE)/64), 256, 0, stream>>>(he_emb, node, w1, b1, Wih_m, Cbuf);
  k3b_edge_score<<<(TT*EE)/4, 256, 0, stream>>>(Cbuf, w2, b2, esc);
  k4_edge_gather<<<(TT*VV)/4, 256, 0, stream>>>(ve, esc, Cbuf, g_in);
  // reuse np_buf for residual; write la into he_emb's slot (no longer needed)
  k5_lstm2<<<VV/256, 256, 0, stream>>>(g_in, Whh_m, bih_m, bhh_m, np_buf, he_emb);
  k6_attn_fc<<<VV/256, 256, 0, stream>>>(he_emb, ain, aout, fcw, fcb, (float*)d_out);
}

// Round 2
// 390.089 us; speedup vs baseline: 2.8635x; 2.8635x over previous
//
#include <hip/hip_runtime.h>
#include <math.h>

// Problem constants
#define TT 4
#define VV 4096
#define EE 4096
#define KK 32
#define DD 8
#define HH 16
#define BERTD 768
#define CATD 784
#define NH 196     // CAT/4 hidden units of EdgeConv MLP
#define NTOT 260   // 196 hidden + 64 pe (Wih_m projection)

__device__ __forceinline__ float sigmoidf_(float x){ return 1.0f/(1.0f+expf(-x)); }
__device__ __forceinline__ float dot4_(float4 a, float4 b){
  return fmaf(a.x,b.x, fmaf(a.y,b.y, fmaf(a.z,b.z, a.w*b.w)));
}

// ---------------------------------------------------------------------------
// K1: price LSTM. (T,V,1) -> new_prices (T,V,16).
// 16 lanes per vertex: lane d owns hidden dim d and gates {d,16+d,32+d,48+d}.
// Weights held in registers (4x16 floats), h broadcast via __shfl width=16.
// Grid: V*16 threads = 256 blocks of 256.
// ---------------------------------------------------------------------------
__global__ void k1_price_lstm(const float* __restrict__ prices,
                              const float* __restrict__ Wih, const float* __restrict__ Whh,
                              const float* __restrict__ bih, const float* __restrict__ bhh,
                              float* __restrict__ np_out){
  int tid  = threadIdx.x;
  int lane = tid & 15;
  int v    = (blockIdx.x*256 + tid) >> 4;
  // per-lane weights: W[gi][d'] = Whh[(gi*16+lane)][d'], wih[gi], b[gi]
  float W[4][16], wih[4], b[4];
#pragma unroll
  for (int gi=0; gi<4; ++gi){
    int j = gi*16 + lane;
    const float4* wr = reinterpret_cast<const float4*>(&Whh[j*16]);
    float4 w0=wr[0], w1=wr[1], w2=wr[2], w3=wr[3];
    W[gi][0]=w0.x; W[gi][1]=w0.y; W[gi][2]=w0.z; W[gi][3]=w0.w;
    W[gi][4]=w1.x; W[gi][5]=w1.y; W[gi][6]=w1.z; W[gi][7]=w1.w;
    W[gi][8]=w2.x; W[gi][9]=w2.y; W[gi][10]=w2.z; W[gi][11]=w2.w;
    W[gi][12]=w3.x; W[gi][13]=w3.y; W[gi][14]=w3.z; W[gi][15]=w3.w;
    wih[gi] = Wih[j];
    b[gi]   = bih[j] + bhh[j];
  }
  float h = 0.f, c = 0.f;
  for (int t=0; t<TT; ++t){
    float x = prices[t*VV + v];
    float a0 = fmaf(x, wih[0], b[0]);
    float a1 = fmaf(x, wih[1], b[1]);
    float a2 = fmaf(x, wih[2], b[2]);
    float a3 = fmaf(x, wih[3], b[3]);
#pragma unroll
    for (int d=0; d<16; ++d){
      float hb = __shfl(h, d, 16);
      a0 = fmaf(hb, W[0][d], a0);
      a1 = fmaf(hb, W[1][d], a1);
      a2 = fmaf(hb, W[2][d], a2);
      a3 = fmaf(hb, W[3][d], a3);
    }
    float ig = sigmoidf_(a0);
    float fg = sigmoidf_(a1);
    float gg = tanhf(a2);
    float og = sigmoidf_(a3);
    c = fmaf(fg, c, ig*gg);
    h = og * tanhf(c);
    np_out[(size_t)(t*VV+v)*16 + lane] = h;
  }
}

// ---------------------------------------------------------------------------
// K2: VertexConv. One block (256 thr) per (t,e). Output he_emb (T,E,16).
// ---------------------------------------------------------------------------
__global__ void k2_vertex_conv(const float* __restrict__ np,
                               const int* __restrict__ mem,
                               const float* __restrict__ tw, const float* __restrict__ tb,
                               const float* __restrict__ cw, const float* __restrict__ cb,
                               float* __restrict__ he_emb){
  int te = blockIdx.x;            // t*E + e
  int t  = te >> 12;
  __shared__ float reg[32][16];
  __shared__ float mult[32][32];
  __shared__ float trans[32][16];
  int tid = threadIdx.x;
  // gather member price embeddings: 32 members x 16 feats
  for (int i = tid; i < 512; i += 256){
    int k = i >> 4, d = i & 15;
    int vid = mem[te*32 + k];
    reg[k][d] = np[(size_t)(t*VV + vid)*16 + d];
  }
  __syncthreads();
  // mult[k][j] = softmax_j( reg[k]·tw[k][j] + tb[k][j] )
  int k = tid >> 3, s = tid & 7;     // 32 rows x 8 lanes, 4 j's per lane
  const float4* rg4 = reinterpret_cast<const float4*>(&reg[k][0]);
  float4 r0 = rg4[0], r1 = rg4[1], r2 = rg4[2], r3 = rg4[3];
  float mv[4];
#pragma unroll
  for (int jj=0; jj<4; ++jj){
    int j = s*4 + jj;
    const float4* w4 = reinterpret_cast<const float4*>(tw + (size_t)(k*32 + j)*16);
    mv[jj] = tb[k*32+j] + dot4_(r0,w4[0]) + dot4_(r1,w4[1]) + dot4_(r2,w4[2]) + dot4_(r3,w4[3]);
  }
  float mx = fmaxf(fmaxf(mv[0],mv[1]), fmaxf(mv[2],mv[3]));
#pragma unroll
  for (int off=1; off<8; off<<=1) mx = fmaxf(mx, __shfl_xor(mx, off));
  float sum = 0.f;
#pragma unroll
  for (int jj=0; jj<4; ++jj){ mv[jj] = expf(mv[jj]-mx); sum += mv[jj]; }
#pragma unroll
  for (int off=1; off<8; off<<=1) sum += __shfl_xor(sum, off);
  float inv = 1.f/sum;
#pragma unroll
  for (int jj=0; jj<4; ++jj) mult[k][s*4+jj] = mv[jj]*inv;
  __syncthreads();
  // trans[k][d] = sum_j mult[k][j]*reg[j][d]
  for (int i = tid; i < 512; i += 256){
    int kk2 = i >> 4, d = i & 15;
    float a = 0.f;
#pragma unroll
    for (int j=0; j<32; ++j) a = fmaf(mult[kk2][j], reg[j][d], a);
    trans[kk2][d] = a;
  }
  __syncthreads();
  // he_emb[d] = cb + sum_k cw[k]*trans[k][d]
  if (tid < 16){
    float a = cb[0];
#pragma unroll
    for (int kq=0; kq<32; ++kq) a = fmaf(cw[kq], trans[kq][tid], a);
    he_emb[(size_t)te*16 + tid] = a;
  }
}

// ---------------------------------------------------------------------------
// K3: fused GEMM. C (16384 x 260) = [he_emb | node_embs] (16384 x 784)
//                                   @ [ec_w1 ; Wih_m]^T  (784 x 260)
// cols 0..195 = pre-relu hidden (+b1), cols 196..259 = pe (no bias).
// 64x64 tile, BK=16, 4x4 register micro-tile.
// ---------------------------------------------------------------------------
__global__ void k3_gemm(const float* __restrict__ he_emb, const float* __restrict__ node,
                        const float* __restrict__ w1, const float* __restrict__ b1,
                        const float* __restrict__ wm, float* __restrict__ C){
  __shared__ float As[16][64];
  __shared__ float Bs[16][64];
  int m0 = blockIdx.y*64, n0 = blockIdx.x*64;
  int tid = threadIdx.x;
  int tx = tid & 15, ty = tid >> 4;
  int lm = tid >> 2;           // 0..63 (row within tile)
  int lk = (tid & 3) * 4;      // 0,4,8,12 (k-quad base)
  float acc[4][4] = {{0.f}};
  for (int kk = 0; kk < 49; ++kk){
    int kbase = kk*16;
    // A tile: row m0+lm, k = kbase+lk .. +3
    {
      int m = m0 + lm;
      int kcol = kbase + lk;
      float4 av;
      if (kcol < 16) av = *reinterpret_cast<const float4*>(&he_emb[(size_t)m*16 + kcol]);
      else           av = *reinterpret_cast<const float4*>(&node[(size_t)m*BERTD + (kcol-16)]);
      As[lk+0][lm]=av.x; As[lk+1][lm]=av.y; As[lk+2][lm]=av.z; As[lk+3][lm]=av.w;
    }
    // B tile: row n0+lm of the stacked weight matrix
    {
      int n = n0 + lm;
      int kcol = kbase + lk;
      float4 bv = make_float4(0.f,0.f,0.f,0.f);
      if (n < NH)        bv = *reinterpret_cast<const float4*>(&w1[(size_t)n*CATD + kcol]);
      else if (n < NTOT) bv = *reinterpret_cast<const float4*>(&wm[(size_t)(n-NH)*CATD + kcol]);
      Bs[lk+0][lm]=bv.x; Bs[lk+1][lm]=bv.y; Bs[lk+2][lm]=bv.z; Bs[lk+3][lm]=bv.w;
    }
    __syncthreads();
#pragma unroll
    for (int k=0; k<16; ++k){
      float4 av = *reinterpret_cast<const float4*>(&As[k][ty*4]);
      float4 bv = *reinterpret_cast<const float4*>(&Bs[k][tx*4]);
      float a[4] = {av.x, av.y, av.z, av.w};
      float b[4] = {bv.x, bv.y, bv.z, bv.w};
#pragma unroll
      for (int i=0;i<4;++i)
#pragma unroll
        for (int j=0;j<4;++j) acc[i][j] = fmaf(a[i], b[j], acc[i][j]);
    }
    __syncthreads();
  }
#pragma unroll
  for (int i=0;i<4;++i){
    int m = m0 + ty*4 + i;
#pragma unroll
    for (int j=0;j<4;++j){
      int n = n0 + tx*4 + j;
      if (n < NTOT){
        float v = acc[i][j];
        if (n < NH) v += b1[n];
        C[(size_t)m*NTOT + n] = v;
      }
    }
  }
}

// ---------------------------------------------------------------------------
// K3b: per-hyperedge score: esc[m] = b2 + sum_n relu(hid[m,n]) * w2[n]
// one wave per row.
// ---------------------------------------------------------------------------
__global__ void k3b_edge_score(const float* __restrict__ C, const float* __restrict__ w2,
                               const float* __restrict__ b2, float* __restrict__ esc){
  int tid = threadIdx.x;
  int lane = tid & 63;
  int row = blockIdx.x*4 + (tid >> 6);
  const float* cr = &C[(size_t)row*NTOT];
  float a = 0.f;
  for (int n = lane; n < NH; n += 64) a = fmaf(fmaxf(cr[n], 0.f), w2[n], a);
#pragma unroll
  for (int off=32; off; off>>=1) a += __shfl_xor(a, off);
  if (lane == 0) esc[row] = a + b2[0];
}

// ---------------------------------------------------------------------------
// K4: per-(t,v): softmax over D=8 edge scores, blend projected rows pe
// (cols 196..259 of C) -> g_in (T,V,64). One wave per (t,v).
// ---------------------------------------------------------------------------
__global__ void k4_edge_gather(const int* __restrict__ ve, const float* __restrict__ esc,
                               const float* __restrict__ C, float* __restrict__ g_in){
  int tid = threadIdx.x;
  int lane = tid & 63;
  int tv = blockIdx.x*4 + (tid >> 6);
  int t = tv >> 12;
  const int* vp = &ve[(size_t)tv*8];
  int e[8]; float w[8];
  float mx = -1e30f;
#pragma unroll
  for (int d=0; d<8; ++d){
    e[d] = vp[d];
    w[d] = esc[(t<<12) + e[d]];
    mx = fmaxf(mx, w[d]);
  }
  float s = 0.f;
#pragma unroll
  for (int d=0; d<8; ++d){ w[d] = expf(w[d]-mx); s += w[d]; }
  float inv = 1.f/s;
  float a = 0.f;
#pragma unroll
  for (int d=0; d<8; ++d)
    a = fmaf(w[d], C[(size_t)((t<<12) + e[d])*NTOT + NH + lane], a);
  g_in[(size_t)tv*64 + lane] = a*inv;
}

// ---------------------------------------------------------------------------
// K5: second LSTM (input already projected to 64 gate pre-activations in g_in)
// + residual new_prices. 16 lanes per vertex, same scheme as K1.
// ---------------------------------------------------------------------------
__global__ void k5_lstm2(const float* __restrict__ g_in, const float* __restrict__ Whh,
                         const float* __restrict__ bih, const float* __restrict__ bhh,
                         const float* __restrict__ np, float* __restrict__ la){
  int tid  = threadIdx.x;
  int lane = tid & 15;
  int v    = (blockIdx.x*256 + tid) >> 4;
  float W[4][16], b[4];
#pragma unroll
  for (int gi=0; gi<4; ++gi){
    int j = gi*16 + lane;
    const float4* wr = reinterpret_cast<const float4*>(&Whh[j*16]);
    float4 w0=wr[0], w1=wr[1], w2=wr[2], w3=wr[3];
    W[gi][0]=w0.x; W[gi][1]=w0.y; W[gi][2]=w0.z; W[gi][3]=w0.w;
    W[gi][4]=w1.x; W[gi][5]=w1.y; W[gi][6]=w1.z; W[gi][7]=w1.w;
    W[gi][8]=w2.x; W[gi][9]=w2.y; W[gi][10]=w2.z; W[gi][11]=w2.w;
    W[gi][12]=w3.x; W[gi][13]=w3.y; W[gi][14]=w3.z; W[gi][15]=w3.w;
    b[gi] = bih[j] + bhh[j];
  }
  float h = 0.f, c = 0.f;
  for (int t=0; t<TT; ++t){
    const float* gi_p = &g_in[(size_t)(t*VV+v)*64];
    float a0 = gi_p[lane]      + b[0];
    float a1 = gi_p[16 + lane] + b[1];
    float a2 = gi_p[32 + lane] + b[2];
    float a3 = gi_p[48 + lane] + b[3];
#pragma unroll
    for (int d=0; d<16; ++d){
      float hb = __shfl(h, d, 16);
      a0 = fmaf(hb, W[0][d], a0);
      a1 = fmaf(hb, W[1][d], a1);
      a2 = fmaf(hb, W[2][d], a2);
      a3 = fmaf(hb, W[3][d], a3);
    }
    float ig = sigmoidf_(a0);
    float fg = sigmoidf_(a1);
    float gg = tanhf(a2);
    float og = sigmoidf_(a3);
    c = fmaf(fg, c, ig*gg);
    h = og * tanhf(c);
    la[(size_t)(t*VV+v)*16 + lane] = h + np[(size_t)(t*VV+v)*16 + lane];
  }
}

// ---------------------------------------------------------------------------
// K6: torchnlp 'general' attention + tanh proj + final FC.
// 16 lanes per vertex; lane d owns dim d of la/mix, row d of the projections.
// ---------------------------------------------------------------------------
__global__ void k6_attn_fc(const float* __restrict__ la, const float* __restrict__ ain,
                           const float* __restrict__ aout, const float* __restrict__ fcw,
                           const float* __restrict__ fcb, float* __restrict__ out){
  __shared__ float s_ain[16*17];   // padded: row j at j*17
  __shared__ float s_aout[16*33];  // padded: row j at j*33
  __shared__ float s_fc[32];
  __shared__ float s_fcb[2];
  int tid = threadIdx.x;
  if (tid < 256) { int j = tid >> 4, d = tid & 15; s_ain[j*17+d] = ain[tid]; }
  for (int i = tid; i < 512; i += 256){ int j = i >> 5, d = i & 31; s_aout[j*33+d] = aout[i]; }
  if (tid < 32) s_fc[tid] = fcw[tid];
  if (tid < 2)  s_fcb[tid] = fcb[tid];
  __syncthreads();
  int lane = tid & 15;
  int v = (blockIdx.x*256 + tid) >> 4;
  float l0 = la[(size_t)(0*VV+v)*16 + lane];
  float l1 = la[(size_t)(1*VV+v)*16 + lane];
  float l2 = la[(size_t)(2*VV+v)*16 + lane];
  float l3 = la[(size_t)(3*VV+v)*16 + lane];
  // q[lane] = sum_d l3[d] * ain[lane][d]
  float q = 0.f;
#pragma unroll
  for (int d=0; d<16; ++d){
    float bb = __shfl(l3, d, 16);
    q = fmaf(bb, s_ain[lane*17+d], q);
  }
  // aw[t] = sum_d q[d]*l t[d]  (16-lane reduce)
  float aw0 = q*l0, aw1 = q*l1, aw2 = q*l2, aw3 = q*l3;
#pragma unroll
  for (int off=1; off<16; off<<=1){
    aw0 += __shfl_xor(aw0, off, 16);
    aw1 += __shfl_xor(aw1, off, 16);
    aw2 += __shfl_xor(aw2, off, 16);
    aw3 += __shfl_xor(aw3, off, 16);
  }
  float mx = fmaxf(fmaxf(aw0,aw1), fmaxf(aw2,aw3));
  aw0 = expf(aw0-mx); aw1 = expf(aw1-mx); aw2 = expf(aw2-mx); aw3 = expf(aw3-mx);
  float inv = 1.f/(aw0+aw1+aw2+aw3);
  float mix = (aw0*l0 + aw1*l1 + aw2*l2 + aw3*l3) * inv;  // dim 'lane'
  // at[lane] = tanh( sum_d mix[d]*aout[lane][d] + q[d]*aout[lane][16+d] )
  float a = 0.f;
#pragma unroll
  for (int d=0; d<16; ++d){
    float m  = __shfl(mix, d, 16);
    float qq = __shfl(q,  d, 16);
    a = fmaf(m,  s_aout[lane*33+d],    a);
    a = fmaf(qq, s_aout[lane*33+16+d], a);
  }
  float at = tanhf(a);
  // out[v][r] = fcb[r] + sum_j at[j]*fcw[r][j]
  float p0 = at * s_fc[lane];
  float p1 = at * s_fc[16+lane];
#pragma unroll
  for (int off=1; off<16; off<<=1){
    p0 += __shfl_xor(p0, off, 16);
    p1 += __shfl_xor(p1, off, 16);
  }
  if (lane == 0){
    out[(size_t)v*2 + 0] = p0 + s_fcb[0];
    out[(size_t)v*2 + 1] = p1 + s_fcb[1];
  }
}

// ---------------------------------------------------------------------------
extern "C" void kernel_launch(void* const* d_in, const int* in_sizes, int n_in,
                              void* d_out, int out_size, void* d_ws, size_t ws_size,
                              hipStream_t stream){
  const float* prices = (const float*)d_in[0];
  const float* node   = (const float*)d_in[1];
  const int*   mem    = (const int*)d_in[2];
  const int*   ve     = (const int*)d_in[3];
  const float* Wih_p  = (const float*)d_in[4];
  const float* Whh_p  = (const float*)d_in[5];
  const float* bih_p  = (const float*)d_in[6];
  const float* bhh_p  = (const float*)d_in[7];
  const float* Wih_m  = (const float*)d_in[8];
  const float* Whh_m  = (const float*)d_in[9];
  const float* bih_m  = (const float*)d_in[10];
  const float* bhh_m  = (const float*)d_in[11];
  const float* tw     = (const float*)d_in[12];
  const float* tb     = (const float*)d_in[13];
  const float* cw     = (const float*)d_in[14];
  const float* cb     = (const float*)d_in[15];
  const float* w1     = (const float*)d_in[16];
  const float* b1     = (const float*)d_in[17];
  const float* w2     = (const float*)d_in[18];
  const float* b2     = (const float*)d_in[19];
  const float* ain    = (const float*)d_in[20];
  const float* aout   = (const float*)d_in[21];
  const float* fcw    = (const float*)d_in[22];
  const float* fcb    = (const float*)d_in[23];

  // workspace layout (floats); total ≈ 25.5 MB
  float* np_buf = (float*)d_ws;                       // T*V*16
  float* he_emb = np_buf + (size_t)TT*VV*HH;          // T*E*16
  float* Cbuf   = he_emb + (size_t)TT*EE*HH;          // 16384*260
  float* esc    = Cbuf   + (size_t)TT*EE*NTOT;        // 16384
  float* g_in   = esc    + (size_t)TT*EE;             // T*V*64
  float* la_buf = g_in   + (size_t)TT*VV*64;          // T*V*16

  k1_price_lstm<<<(VV*16)/256, 256, 0, stream>>>(prices, Wih_p, Whh_p, bih_p, bhh_p, np_buf);
  k2_vertex_conv<<<TT*EE, 256, 0, stream>>>(np_buf, mem, tw, tb, cw, cb, he_emb);
  k3_gemm<<<dim3(5, (TT*EE)/64), 256, 0, stream>>>(he_emb, node, w1, b1, Wih_m, Cbuf);
  k3b_edge_score<<<(TT*EE)/4, 256, 0, stream>>>(Cbuf, w2, b2, esc);
  k4_edge_gather<<<(TT*VV)/4, 256, 0, stream>>>(ve, esc, Cbuf, g_in);
  k5_lstm2<<<(VV*16)/256, 256, 0, stream>>>(g_in, Whh_m, bih_m, bhh_m, np_buf, la_buf);
  k6_attn_fc<<<(VV*16)/256, 256, 0, stream>>>(la_buf, ain, aout, fcw, fcb, (float*)d_out);
}